// Round 1
// baseline (305.478 us; speedup 1.0000x reference)
//
#include <hip/hip_runtime.h>
#include <hip/hip_bf16.h>

// RNN: B=1024, T=512, H=128, +4 autoregressive steps -> out (1024, 516)
// Round 14: latency-bound diagnosis (all pipes <11% busy, ~716 cyc/step vs
// ~200 issue cyc). Fill the ~500 stall cycles/step with a second independent
// batch tile per block (BM=32, 2 tiles interleaved per wave between the same
// barriers). ybuf dropped (LDS 157->91 KB): y stored directly to global by
// the decoder waves. Decoder MFMA tile split: wave7 = tile A, wave6 = tile B
// (rebalance). Kept from R13: fixed kf order (no runtime frag indexing ->
// no scratch), pre-scaled W/b/w0 by 2*log2e, phase-batched epilogue, fp16
// pipeline + XOR-swizzled hbuf + v_cvt_pkrtz packing.

#define BB 1024
#define TT 512
#define HH 128
#define TOUT 516
#define BM 32          // batch rows per block = 2 MFMA tiles of 16
#define XSTR 513       // xs stride (dwords)
#define PQS 36         // pq row stride (dwords)
#define TWOLOG2E 2.885390082f

typedef __attribute__((ext_vector_type(8))) _Float16 f16x8;
typedef __attribute__((ext_vector_type(4))) float f32x4;

#define MFMA16(A_, B_, C_) __builtin_amdgcn_mfma_f32_16x16x32_f16(A_, B_, C_, 0, 0, 0)

__global__ void detect_dtype(const void* w, int* flag) {
    const int lane = threadIdx.x;  // 64 threads
    const __hip_bfloat16* p = (const __hip_bfloat16*)w;
    const float v0 = __bfloat162float(p[lane]);
    const float v1 = __bfloat162float(p[64 + lane]);
    const bool bad = !(fabsf(v0) < 100.0f) || !(fabsf(v1) < 100.0f);
    const unsigned long long m = __ballot(bad);
    if (lane == 0) *flag = (__popcll(m) > 4) ? 1 : 0;  // 1 => data is fp32
}

template <bool F32>
__device__ __forceinline__ float ldg(const void* p, int idx) {
    if (F32) return ((const float*)p)[idx];
    return __bfloat162float(((const __hip_bfloat16*)p)[idx]);
}

template <bool F32>
__device__ __forceinline__ void stg(void* p, int idx, float v) {
    if (F32) ((float*)p)[idx] = v;
    else     ((__hip_bfloat16*)p)[idx] = __float2bfloat16(v);
}

// sum of pq row [0..31] (16B-aligned)
__device__ __forceinline__ float red32(const float* pqrow) {
    const f32x4* v = (const f32x4*)pqrow;
    const f32x4 s = ((v[0] + v[1]) + (v[2] + v[3])) + ((v[4] + v[5]) + (v[6] + v[7]));
    return (s[0] + s[1]) + (s[2] + s[3]);
}

// One RNN step for BOTH batch tiles (A = rows 0..15, B = rows 16..31).
// T_: timestep; CUR_: h read buffer; WRITEY_: dec waves emit y[T_-1];
// DOPQ_: lanes write decoder partials to pq (tail); READX_: prefetch
// xs[T_+1]; TAILX_: xv from pq reduce (feedback).
// hbuf swizzle: logical 16B-chunk c of row r lives at physical chunk (c^r)&15.
// acc accumulates 2*log2e*z; h = 1 - 2/(exp2(acc)+1).
#define STEP(T_, CUR_, WRITEY_, DOPQ_, READX_, TAILX_) do {                     \
    f16x8 bfragA[4], bfragB[4];                                                 \
    _Pragma("unroll")                                                           \
    for (int kf = 0; kf < 4; ++kf) {                                            \
        const int co = ((((kf << 2) | q) ^ n) & 15) << 3;                       \
        bfragA[kf] = *(const f16x8*)&hbuf[CUR_][n][co];                         \
        bfragB[kf] = *(const f16x8*)&hbuf[CUR_][16 + n][co];                    \
    }                                                                           \
    float xnA = 0.0f, xnB = 0.0f;                                               \
    if (READX_) { xnA = xs[n][(T_) + 1]; xnB = xs[16 + n][(T_) + 1]; }          \
    float xvA, xvB;                                                             \
    if (TAILX_) { xvA = red32(&pq[((T_) - 1) & 1][n][0]) + dbv;                 \
                  xvB = red32(&pq[((T_) - 1) & 1][16 + n][0]) + dbv; }          \
    else        { xvA = xprefA; xvB = xprefB; }                                 \
    f32x4 a0A, a1A, a0B, a1B;                                                   \
    _Pragma("unroll")                                                           \
    for (int r = 0; r < 4; ++r) { a0A[r] = fmaf(xvA, w0v[r], bsum[r]);          \
                                  a0B[r] = fmaf(xvB, w0v[r], bsum[r]); }        \
    a1A = (f32x4){0.f, 0.f, 0.f, 0.f};                                          \
    a1B = (f32x4){0.f, 0.f, 0.f, 0.f};                                          \
    a0A = MFMA16(wa[0], bfragA[0], a0A);                                        \
    a0B = MFMA16(wa[0], bfragB[0], a0B);                                        \
    a1A = MFMA16(wa[1], bfragA[1], a1A);                                        \
    a1B = MFMA16(wa[1], bfragB[1], a1B);                                        \
    a0A = MFMA16(wa[2], bfragA[2], a0A);                                        \
    a0B = MFMA16(wa[2], bfragB[2], a0B);                                        \
    a1A = MFMA16(wa[3], bfragA[3], a1A);                                        \
    a1B = MFMA16(wa[3], bfragB[3], a1B);                                        \
    if (WRITEY_) {                                                              \
        if (isw7) {  /* dec tile A: y[T_-1] = dec . h_old(A) */                 \
            f32x4 dA0 = (f32x4){0.f, 0.f, 0.f, 0.f};                            \
            f32x4 dA1 = (f32x4){0.f, 0.f, 0.f, 0.f};                            \
            dA0 = MFMA16(wa_d[0], bfragA[0], dA0);                              \
            dA1 = MFMA16(wa_d[1], bfragA[1], dA1);                              \
            dA0 = MFMA16(wa_d[2], bfragA[2], dA0);                              \
            dA1 = MFMA16(wa_d[3], bfragA[3], dA1);                              \
            if (q == 0)                                                         \
                stg<F32>(out, (row0 + n) * TOUT + (T_) - 1,                     \
                         dA0[0] + dA1[0] + dbv);                                \
        }                                                                       \
        if (isw6) {  /* dec tile B */                                           \
            f32x4 dB0 = (f32x4){0.f, 0.f, 0.f, 0.f};                            \
            f32x4 dB1 = (f32x4){0.f, 0.f, 0.f, 0.f};                            \
            dB0 = MFMA16(wa_d[0], bfragB[0], dB0);                              \
            dB1 = MFMA16(wa_d[1], bfragB[1], dB1);                              \
            dB0 = MFMA16(wa_d[2], bfragB[2], dB0);                              \
            dB1 = MFMA16(wa_d[3], bfragB[3], dB1);                              \
            if (q == 0)                                                         \
                stg<F32>(out, (row0 + 16 + n) * TOUT + (T_) - 1,                \
                         dB0[0] + dB1[0] + dbv);                                \
        }                                                                       \
    }                                                                           \
    float zsA[4], zsB[4], exA[4], exB[4], rcA[4], rcB[4], hvA[4], hvB[4];       \
    _Pragma("unroll")                                                           \
    for (int r = 0; r < 4; ++r) { zsA[r] = a0A[r] + a1A[r];                     \
                                  zsB[r] = a0B[r] + a1B[r]; }                   \
    _Pragma("unroll")                                                           \
    for (int r = 0; r < 4; ++r) { exA[r] = __builtin_amdgcn_exp2f(zsA[r]);      \
                                  exB[r] = __builtin_amdgcn_exp2f(zsB[r]); }    \
    _Pragma("unroll")                                                           \
    for (int r = 0; r < 4; ++r) { rcA[r] = __builtin_amdgcn_rcpf(exA[r] + 1.0f);\
                                  rcB[r] = __builtin_amdgcn_rcpf(exB[r] + 1.0f);}\
    _Pragma("unroll")                                                           \
    for (int r = 0; r < 4; ++r) { hvA[r] = fmaf(-2.0f, rcA[r], 1.0f);           \
                                  hvB[r] = fmaf(-2.0f, rcB[r], 1.0f); }         \
    float pA = 0.0f, pB = 0.0f;                                                 \
    if (DOPQ_) {                                                                \
        _Pragma("unroll")                                                       \
        for (int r = 0; r < 4; ++r) { pA = fmaf(decv[r], hvA[r], pA);           \
                                      pB = fmaf(decv[r], hvB[r], pB); }         \
    }                                                                           \
    uint2 pkA, pkB;                                                             \
    pkA.x = __builtin_bit_cast(unsigned, __builtin_amdgcn_cvt_pkrtz(hvA[0], hvA[1])); \
    pkA.y = __builtin_bit_cast(unsigned, __builtin_amdgcn_cvt_pkrtz(hvA[2], hvA[3])); \
    pkB.x = __builtin_bit_cast(unsigned, __builtin_amdgcn_cvt_pkrtz(hvB[0], hvB[1])); \
    pkB.y = __builtin_bit_cast(unsigned, __builtin_amdgcn_cvt_pkrtz(hvB[2], hvB[3])); \
    {                                                                           \
        const int wo = ((((2 * wv + (q >> 1)) ^ n) & 15) << 3) + ((q & 1) << 2);\
        *(uint2*)&hbuf[(CUR_) ^ 1][n][wo]      = pkA;                           \
        *(uint2*)&hbuf[(CUR_) ^ 1][16 + n][wo] = pkB;                           \
    }                                                                           \
    if (DOPQ_) { pq[(T_) & 1][n][wv * 4 + q]      = pA;                         \
                 pq[(T_) & 1][16 + n][wv * 4 + q] = pB; }                       \
    if (READX_) { xprefA = xnA; xprefB = xnB; }                                 \
    __syncthreads();                                                            \
} while (0)

template <bool F32>
__device__ void rnn_body(const void* __restrict__ xg, const void* __restrict__ h0,
                         const void* __restrict__ w0, const void* __restrict__ b0,
                         const void* __restrict__ W,  const void* __restrict__ bw,
                         const void* __restrict__ dw, const void* __restrict__ db,
                         void* __restrict__ out,
                         float (*xs)[XSTR], _Float16 (*hbuf)[BM][HH],
                         float (*pq)[BM][PQS])
{
    const int tid  = threadIdx.x;
    const int lane = tid & 63;
    const int wv   = tid >> 6;        // 0..7 (= m-tile index)
    const int q    = lane >> 4;       // 0..3
    const int n    = lane & 15;       // batch col within tile / A-row-in-tile
    const int row0 = blockIdx.x * BM;
    const bool isw7 = (wv == 7);      // wave-uniform: dec tile A
    const bool isw6 = (wv == 6);      // wave-uniform: dec tile B

    // stage x (fp32 in LDS), 32 rows
    for (int idx = tid; idx < BM * TT; idx += 512) {
        const int rr = idx >> 9, t2 = idx & (TT - 1);
        xs[rr][t2] = ldg<F32>(xg, (row0 + rr) * TT + t2);
    }
    // stage h0 as fp16 (swizzled: chunk c of row rr -> (c^rr)&15)
    for (int idx = tid; idx < BM * HH; idx += 512) {
        const int rr = idx >> 7, ii = idx & (HH - 1);
        const int po = ((((ii >> 3) ^ rr) & 15) << 3) + (ii & 7);
        hbuf[0][rr][po] = (_Float16)ldg<F32>(h0, (row0 + rr) * HH + ii);
    }

    // preload W fragments (A-operand: A[m=lane&15][k=q*8+j]) as fp16,
    // PRE-SCALED by 2*log2e so the accumulator is the exp2 argument.
    // Shared by both batch tiles.
    f16x8 wa[4];
    {
        const int ia = wv * 16 + n;   // W row (output unit)
        #pragma unroll
        for (int kf = 0; kf < 4; ++kf) {
            const int kb = kf * 32 + q * 8;
            f16x8 fr;
            #pragma unroll
            for (int j = 0; j < 8; ++j)
                fr[j] = (_Float16)(TWOLOG2E * ldg<F32>(W, ia * HH + kb + j));
            wa[kf] = fr;
        }
    }
    // dec tile (waves 6 and 7): A row 0 = dec_w (UNscaled - operates on h),
    // rows 1..15 = 0
    f16x8 wa_d[4] = {};
    if (wv >= 6) {
        #pragma unroll
        for (int kf = 0; kf < 4; ++kf) {
            const int kb = kf * 32 + q * 8;
            f16x8 fr = {};
            if (n == 0) {
                #pragma unroll
                for (int j = 0; j < 8; ++j) fr[j] = (_Float16)ldg<F32>(dw, kb + j);
            }
            wa_d[kf] = fr;
        }
    }
    // epilogue constants (C-layout rows: i = wv*16 + q*4 + r), pre-scaled
    float bsum[4], w0v[4], decv[4];
    #pragma unroll
    for (int r = 0; r < 4; ++r) {
        const int ic = wv * 16 + q * 4 + r;
        bsum[r] = TWOLOG2E * (ldg<F32>(b0, ic) + ldg<F32>(bw, ic));
        w0v[r]  = TWOLOG2E * ldg<F32>(w0, ic);
        decv[r] = ldg<F32>(dw, ic);
    }
    const float dbv = ldg<F32>(db, 0);

    __syncthreads();

    float xprefA = xs[n][0];
    float xprefB = xs[16 + n][0];

    // t = 0: no y yet, no pq
    STEP(0, 0, false, false, true, false);

    // main: t = 1..510, compile-time cur (odd reads buf1, even reads buf0)
    #pragma unroll 1
    for (int t = 1; t < 511; t += 2) {
        STEP(t,     1, true, false, true, false);
        STEP(t + 1, 0, true, false, true, false);
    }

    // t = 511: last x step; start pq for tail feedback
    STEP(511, 1, true, true, false, false);

    // tail: t = 512..515, xv = y[t-1] via pq reduce
    #pragma unroll 1
    for (int t = 512; t < 516; ++t) {
        STEP(t, t & 1, true, true, false, true);
    }

    // final y[515] (pq[1] holds step-515 partials; STEP ended with a barrier)
    if (isw7 && q == 0)
        stg<F32>(out, (row0 + n) * TOUT + TOUT - 1, red32(&pq[1][n][0]) + dbv);
    if (isw6 && q == 0)
        stg<F32>(out, (row0 + 16 + n) * TOUT + TOUT - 1, red32(&pq[1][16 + n][0]) + dbv);
}

__global__ __launch_bounds__(512, 2)
void rnn_mfma(const void* __restrict__ xg, const void* __restrict__ h0,
              const void* __restrict__ w0, const void* __restrict__ b0,
              const void* __restrict__ W,  const void* __restrict__ bw,
              const void* __restrict__ dw, const void* __restrict__ db,
              void* __restrict__ out, const int* __restrict__ flag)
{
    __shared__ float xs[BM][XSTR];                          // 65.7 KB
    __shared__ __align__(16) _Float16 hbuf[2][BM][HH];      // 16 KB
    __shared__ __align__(16) float pq[2][BM][PQS];          // 9.2 KB

    const int f = *(volatile const int*)flag;  // block-uniform
    if (f) rnn_body<true >(xg, h0, w0, b0, W, bw, dw, db, out, xs, hbuf, pq);
    else   rnn_body<false>(xg, h0, w0, b0, W, bw, dw, db, out, xs, hbuf, pq);
}

extern "C" void kernel_launch(void* const* d_in, const int* in_sizes, int n_in,
                              void* d_out, int out_size, void* d_ws, size_t ws_size,
                              hipStream_t stream) {
    int* flag = (int*)d_ws;
    detect_dtype<<<1, 64, 0, stream>>>(d_in[4], flag);  // probe fc_w
    rnn_mfma<<<BB / BM, 512, 0, stream>>>(d_in[0], d_in[1], d_in[2], d_in[3],
                                          d_in[4], d_in[5], d_in[6], d_in[7],
                                          d_out, flag);
}

// Round 3
// 274.030 us; speedup vs baseline: 1.1148x; 1.1148x over previous
//
#include <hip/hip_runtime.h>
#include <hip/hip_bf16.h>

// RNN: B=1024, T=512, H=128, +4 autoregressive steps -> out (1024, 516)
// Round 15 (resubmit; R15 bench was an infra failure, no data).
// LDS-pipe diagnosis: R14's regression (+447 cy/step) matched the added
// LDS-pipe occupancy (+430 cy) almost exactly -> the shared LDS read pipe
// is the serialized resource. R13 was already ~67% LDS-bound because all
// 8 waves read the IDENTICAL B-fragment (full h-tile): M-split 8 ways =
// 8x redundant reads. Fix: 4 waves x 2 M-tiles each (BM=16, 256 thr,
// grid=64). B read once per wave, amortized over 2 M-tiles -> LDS pipe
// ~478 -> ~260 cy/step. Decoder MFMA on wave 3. y stored direct to global
// (no ybuf; kept from R14 - passed harness). Kept: fixed kf order (no
// runtime frag indexing), pre-scaled W/b/w0 by 2*log2e, phase-batched
// epilogue, fp16 pipeline + XOR-swizzled hbuf + v_cvt_pkrtz packing.

#define BB 1024
#define TT 512
#define HH 128
#define TOUT 516
#define BM 16          // batch rows per block (one 16-wide MFMA N-tile)
#define XSTR 513       // xs stride (dwords)
#define PQS 20         // pq row stride (dwords): 16 partials + pad
#define TWOLOG2E 2.885390082f

typedef __attribute__((ext_vector_type(8))) _Float16 f16x8;
typedef __attribute__((ext_vector_type(4))) float f32x4;

#define MFMA16(A_, B_, C_) __builtin_amdgcn_mfma_f32_16x16x32_f16(A_, B_, C_, 0, 0, 0)

__global__ void detect_dtype(const void* w, int* flag) {
    const int lane = threadIdx.x;  // 64 threads
    const __hip_bfloat16* p = (const __hip_bfloat16*)w;
    const float v0 = __bfloat162float(p[lane]);
    const float v1 = __bfloat162float(p[64 + lane]);
    const bool bad = !(fabsf(v0) < 100.0f) || !(fabsf(v1) < 100.0f);
    const unsigned long long m = __ballot(bad);
    if (lane == 0) *flag = (__popcll(m) > 4) ? 1 : 0;  // 1 => data is fp32
}

template <bool F32>
__device__ __forceinline__ float ldg(const void* p, int idx) {
    if (F32) return ((const float*)p)[idx];
    return __bfloat162float(((const __hip_bfloat16*)p)[idx]);
}

template <bool F32>
__device__ __forceinline__ void stg(void* p, int idx, float v) {
    if (F32) ((float*)p)[idx] = v;
    else     ((__hip_bfloat16*)p)[idx] = __float2bfloat16(v);
}

// sum of pq row [0..15] (16B-aligned)
__device__ __forceinline__ float red16(const float* pqrow) {
    const f32x4* v = (const f32x4*)pqrow;
    const f32x4 s = (v[0] + v[1]) + (v[2] + v[3]);
    return (s[0] + s[1]) + (s[2] + s[3]);
}

// One RNN step. Wave wv owns M-tiles m0=2wv, m1=2wv+1 (output units
// 32wv..32wv+31). T_: timestep; CUR_: h read buffer; WRITEY_: wave 3 emits
// y[T_-1] direct to global; DOPQ_: lanes write decoder partials to pq
// (tail); READX_: prefetch xs[T_+1]; TAILX_: xv from pq reduce (feedback).
// hbuf swizzle: logical 16B-chunk c of row r lives at physical chunk (c^r)&15.
// acc accumulates 2*log2e*z; h = 1 - 2/(exp2(acc)+1).
#define STEP(T_, CUR_, WRITEY_, DOPQ_, READX_, TAILX_) do {                     \
    f16x8 bfrag[4];                                                             \
    _Pragma("unroll")                                                           \
    for (int kf = 0; kf < 4; ++kf)                                              \
        bfrag[kf] = *(const f16x8*)&hbuf[CUR_][n][((((kf << 2) | q) ^ n) & 15) << 3]; \
    float xnext = 0.0f;                                                         \
    if (READX_) xnext = xs[n][(T_) + 1];                                        \
    float xv;                                                                   \
    if (TAILX_) xv = red16(&pq[((T_) - 1) & 1][n][0]) + dbv;                    \
    else        xv = xpref;                                                     \
    f32x4 a00, a01, a10, a11;                                                   \
    _Pragma("unroll")                                                           \
    for (int r = 0; r < 4; ++r) { a00[r] = fmaf(xv, w0v0[r], bsum0[r]);         \
                                  a10[r] = fmaf(xv, w0v1[r], bsum1[r]); }       \
    a01 = (f32x4){0.f, 0.f, 0.f, 0.f};                                          \
    a11 = (f32x4){0.f, 0.f, 0.f, 0.f};                                          \
    a00 = MFMA16(wa0[0], bfrag[0], a00);                                        \
    a10 = MFMA16(wa1[0], bfrag[0], a10);                                        \
    a01 = MFMA16(wa0[1], bfrag[1], a01);                                        \
    a11 = MFMA16(wa1[1], bfrag[1], a11);                                        \
    a00 = MFMA16(wa0[2], bfrag[2], a00);                                        \
    a10 = MFMA16(wa1[2], bfrag[2], a10);                                        \
    a01 = MFMA16(wa0[3], bfrag[3], a01);                                        \
    a11 = MFMA16(wa1[3], bfrag[3], a11);                                        \
    if (isw3 && (WRITEY_)) {  /* dec tile: y[T_-1] = dec . h_old */             \
        f32x4 dA0 = (f32x4){0.f, 0.f, 0.f, 0.f};                                \
        f32x4 dA1 = (f32x4){0.f, 0.f, 0.f, 0.f};                                \
        dA0 = MFMA16(wa_d[0], bfrag[0], dA0);                                   \
        dA1 = MFMA16(wa_d[1], bfrag[1], dA1);                                   \
        dA0 = MFMA16(wa_d[2], bfrag[2], dA0);                                   \
        dA1 = MFMA16(wa_d[3], bfrag[3], dA1);                                   \
        if (q == 0)                                                             \
            stg<F32>(out, (row0 + n) * TOUT + (T_) - 1, dA0[0] + dA1[0] + dbv); \
    }                                                                           \
    float zs0[4], zs1[4], ex0[4], ex1[4], rc0[4], rc1[4], hv0[4], hv1[4];       \
    _Pragma("unroll")                                                           \
    for (int r = 0; r < 4; ++r) { zs0[r] = a00[r] + a01[r];                     \
                                  zs1[r] = a10[r] + a11[r]; }                   \
    _Pragma("unroll")                                                           \
    for (int r = 0; r < 4; ++r) { ex0[r] = __builtin_amdgcn_exp2f(zs0[r]);      \
                                  ex1[r] = __builtin_amdgcn_exp2f(zs1[r]); }    \
    _Pragma("unroll")                                                           \
    for (int r = 0; r < 4; ++r) { rc0[r] = __builtin_amdgcn_rcpf(ex0[r] + 1.0f);\
                                  rc1[r] = __builtin_amdgcn_rcpf(ex1[r] + 1.0f);}\
    _Pragma("unroll")                                                           \
    for (int r = 0; r < 4; ++r) { hv0[r] = fmaf(-2.0f, rc0[r], 1.0f);           \
                                  hv1[r] = fmaf(-2.0f, rc1[r], 1.0f); }         \
    float p = 0.0f;                                                             \
    if (DOPQ_) {                                                                \
        _Pragma("unroll")                                                       \
        for (int r = 0; r < 4; ++r) { p = fmaf(decv0[r], hv0[r], p);            \
                                      p = fmaf(decv1[r], hv1[r], p); }          \
    }                                                                           \
    uint2 pk0, pk1;                                                             \
    pk0.x = __builtin_bit_cast(unsigned, __builtin_amdgcn_cvt_pkrtz(hv0[0], hv0[1])); \
    pk0.y = __builtin_bit_cast(unsigned, __builtin_amdgcn_cvt_pkrtz(hv0[2], hv0[3])); \
    pk1.x = __builtin_bit_cast(unsigned, __builtin_amdgcn_cvt_pkrtz(hv1[0], hv1[1])); \
    pk1.y = __builtin_bit_cast(unsigned, __builtin_amdgcn_cvt_pkrtz(hv1[2], hv1[3])); \
    {   /* m0 -> logical chunk 4wv+(q>>1); m1 -> 4wv+2+(q>>1) */                \
        const int lo = ((q & 1) << 2);                                          \
        const int c0 = ((((4 * wv) | (q >> 1)) ^ n) & 15) << 3;                 \
        const int c1 = ((((4 * wv + 2) | (q >> 1)) ^ n) & 15) << 3;             \
        *(uint2*)&hbuf[(CUR_) ^ 1][n][c0 + lo] = pk0;                           \
        *(uint2*)&hbuf[(CUR_) ^ 1][n][c1 + lo] = pk1;                           \
    }                                                                           \
    if (DOPQ_) pq[(T_) & 1][n][wv * 4 + q] = p;                                 \
    if (READX_) xpref = xnext;                                                  \
    __syncthreads();                                                            \
} while (0)

template <bool F32>
__device__ void rnn_body(const void* __restrict__ xg, const void* __restrict__ h0,
                         const void* __restrict__ w0, const void* __restrict__ b0,
                         const void* __restrict__ W,  const void* __restrict__ bw,
                         const void* __restrict__ dw, const void* __restrict__ db,
                         void* __restrict__ out,
                         float (*xs)[XSTR], _Float16 (*hbuf)[BM][HH],
                         float (*pq)[BM][PQS])
{
    const int tid  = threadIdx.x;
    const int lane = tid & 63;
    const int wv   = tid >> 6;        // 0..3 (owns M-tiles 2wv, 2wv+1)
    const int q    = lane >> 4;       // 0..3
    const int n    = lane & 15;       // batch col / B-col / A-row-in-tile
    const int row0 = blockIdx.x * BM;
    const bool isw3 = (wv == 3);      // wave-uniform: decoder wave

    // stage x (fp32 in LDS)
    for (int idx = tid; idx < BM * TT; idx += 256) {
        const int rr = idx >> 9, t2 = idx & (TT - 1);
        xs[rr][t2] = ldg<F32>(xg, (row0 + rr) * TT + t2);
    }
    // stage h0 as fp16 (swizzled: chunk c of row rr -> (c^rr)&15)
    for (int idx = tid; idx < BM * HH; idx += 256) {
        const int rr = idx >> 7, ii = idx & (HH - 1);
        const int po = ((((ii >> 3) ^ rr) & 15) << 3) + (ii & 7);
        hbuf[0][rr][po] = (_Float16)ldg<F32>(h0, (row0 + rr) * HH + ii);
    }

    // preload W fragments for BOTH M-tiles (A-operand: A[m=lane&15][k=q*8+j])
    // as fp16, PRE-SCALED by 2*log2e so the accumulator is the exp2 argument.
    f16x8 wa0[4], wa1[4];
    {
        const int ia0 = 32 * wv + n;       // W row (output unit), tile m0
        const int ia1 = 32 * wv + 16 + n;  // tile m1
        #pragma unroll
        for (int kf = 0; kf < 4; ++kf) {
            const int kb = kf * 32 + q * 8;
            f16x8 fr0, fr1;
            #pragma unroll
            for (int j = 0; j < 8; ++j) {
                fr0[j] = (_Float16)(TWOLOG2E * ldg<F32>(W, ia0 * HH + kb + j));
                fr1[j] = (_Float16)(TWOLOG2E * ldg<F32>(W, ia1 * HH + kb + j));
            }
            wa0[kf] = fr0;
            wa1[kf] = fr1;
        }
    }
    // dec tile (wave 3): A row 0 = dec_w (UNscaled - operates on h), rows 1..15 = 0
    f16x8 wa_d[4] = {};
    if (isw3) {
        #pragma unroll
        for (int kf = 0; kf < 4; ++kf) {
            const int kb = kf * 32 + q * 8;
            f16x8 fr = {};
            if (n == 0) {
                #pragma unroll
                for (int j = 0; j < 8; ++j) fr[j] = (_Float16)ldg<F32>(dw, kb + j);
            }
            wa_d[kf] = fr;
        }
    }
    // epilogue constants (C rows: i = 32wv + {0,16} + q*4 + r), pre-scaled
    float bsum0[4], w0v0[4], decv0[4], bsum1[4], w0v1[4], decv1[4];
    #pragma unroll
    for (int r = 0; r < 4; ++r) {
        const int ic0 = 32 * wv + q * 4 + r;
        const int ic1 = ic0 + 16;
        bsum0[r] = TWOLOG2E * (ldg<F32>(b0, ic0) + ldg<F32>(bw, ic0));
        bsum1[r] = TWOLOG2E * (ldg<F32>(b0, ic1) + ldg<F32>(bw, ic1));
        w0v0[r]  = TWOLOG2E * ldg<F32>(w0, ic0);
        w0v1[r]  = TWOLOG2E * ldg<F32>(w0, ic1);
        decv0[r] = ldg<F32>(dw, ic0);
        decv1[r] = ldg<F32>(dw, ic1);
    }
    const float dbv = ldg<F32>(db, 0);

    __syncthreads();

    float xpref = xs[n][0];

    // t = 0: no y yet, no pq
    STEP(0, 0, false, false, true, false);

    // main: t = 1..510, compile-time cur (odd reads buf1, even reads buf0)
    #pragma unroll 1
    for (int t = 1; t < 511; t += 2) {
        STEP(t,     1, true, false, true, false);
        STEP(t + 1, 0, true, false, true, false);
    }

    // t = 511: last x step; start pq for tail feedback
    STEP(511, 1, true, true, false, false);

    // tail: t = 512..515, xv = y[t-1] via pq reduce
    #pragma unroll 1
    for (int t = 512; t < 516; ++t) {
        STEP(t, t & 1, true, true, false, true);
    }

    // final y[515] (pq[1] holds step-515 partials; STEP ended with a barrier)
    if (isw3 && q == 0)
        stg<F32>(out, (row0 + n) * TOUT + TOUT - 1, red16(&pq[1][n][0]) + dbv);
}

__global__ __launch_bounds__(256, 1)
void rnn_mfma(const void* __restrict__ xg, const void* __restrict__ h0,
              const void* __restrict__ w0, const void* __restrict__ b0,
              const void* __restrict__ W,  const void* __restrict__ bw,
              const void* __restrict__ dw, const void* __restrict__ db,
              void* __restrict__ out, const int* __restrict__ flag)
{
    __shared__ float xs[BM][XSTR];                          // 32.8 KB
    __shared__ __align__(16) _Float16 hbuf[2][BM][HH];      // 8 KB
    __shared__ __align__(16) float pq[2][BM][PQS];          // 2.6 KB

    const int f = *(volatile const int*)flag;  // block-uniform
    if (f) rnn_body<true >(xg, h0, w0, b0, W, bw, dw, db, out, xs, hbuf, pq);
    else   rnn_body<false>(xg, h0, w0, b0, W, bw, dw, db, out, xs, hbuf, pq);
}

extern "C" void kernel_launch(void* const* d_in, const int* in_sizes, int n_in,
                              void* d_out, int out_size, void* d_ws, size_t ws_size,
                              hipStream_t stream) {
    int* flag = (int*)d_ws;
    detect_dtype<<<1, 64, 0, stream>>>(d_in[4], flag);  // probe fc_w
    rnn_mfma<<<BB / BM, 256, 0, stream>>>(d_in[0], d_in[1], d_in[2], d_in[3],
                                          d_in[4], d_in[5], d_in[6], d_in[7],
                                          d_out, flag);
}

// Round 4
// 220.503 us; speedup vs baseline: 1.3854x; 1.2428x over previous
//
#include <hip/hip_runtime.h>
#include <hip/hip_bf16.h>

// RNN: B=1024, T=512, H=128, +4 autoregressive steps -> out (1024, 516)
// Round 16: back to the 8-wave M-split (R13, 154us = best). Model: step =
// LDS-pipe drain (~450 cy, 8 waves x 4xb128 h-reads, irreducible) + one
// wave's tail chain (~270 cy). R15 proved 4 waves (1/SIMD) exposes all
// latency (979 cy). Attack the tail instead:
//  - DEFERRED DEC: wave 7's dec MFMA + y store moved AFTER the barrier
//    (computed from the previous step's bfrag, still in registers) ->
//    overlaps the next step's read-drain on the idle MFMA pipe; removes
//    the per-step wave-7 straggler from the barrier path.
//  - QUAD X: xs read as one ds_read_b128 per 4 steps (XSTR 516 for 16B
//    alignment) instead of a b32 every step -> fewer ops in the drain.
//  - ybuf dropped; y stored direct to global (validated R14/R15).
// Kept: fixed kf order (no runtime frag indexing -> no scratch), W/b/w0
// pre-scaled by 2*log2e, phase-batched epilogue, fp16 pipeline +
// XOR-swizzled hbuf + v_cvt_pkrtz packing.

#define BB 1024
#define TT 512
#define HH 128
#define TOUT 516
#define BM 16          // batch rows per block (one 16-wide MFMA N-tile)
#define XSTR 516       // xs stride (dwords); 516*4 % 16 == 0 -> b128-aligned rows
#define PQS 36         // pq row stride (dwords): 32 partials + pad
#define TWOLOG2E 2.885390082f

typedef __attribute__((ext_vector_type(8))) _Float16 f16x8;
typedef __attribute__((ext_vector_type(4))) float f32x4;

#define MFMA16(A_, B_, C_) __builtin_amdgcn_mfma_f32_16x16x32_f16(A_, B_, C_, 0, 0, 0)

__global__ void detect_dtype(const void* w, int* flag) {
    const int lane = threadIdx.x;  // 64 threads
    const __hip_bfloat16* p = (const __hip_bfloat16*)w;
    const float v0 = __bfloat162float(p[lane]);
    const float v1 = __bfloat162float(p[64 + lane]);
    const bool bad = !(fabsf(v0) < 100.0f) || !(fabsf(v1) < 100.0f);
    const unsigned long long m = __ballot(bad);
    if (lane == 0) *flag = (__popcll(m) > 4) ? 1 : 0;  // 1 => data is fp32
}

template <bool F32>
__device__ __forceinline__ float ldg(const void* p, int idx) {
    if (F32) return ((const float*)p)[idx];
    return __bfloat162float(((const __hip_bfloat16*)p)[idx]);
}

template <bool F32>
__device__ __forceinline__ void stg(void* p, int idx, float v) {
    if (F32) ((float*)p)[idx] = v;
    else     ((__hip_bfloat16*)p)[idx] = __float2bfloat16(v);
}

// sum of pq row [0..31] (16B-aligned)
__device__ __forceinline__ float red32(const float* pqrow) {
    const f32x4* v = (const f32x4*)pqrow;
    const f32x4 s = ((v[0] + v[1]) + (v[2] + v[3])) + ((v[4] + v[5]) + (v[6] + v[7]));
    return (s[0] + s[1]) + (s[2] + s[3]);
}

// One RNN step. Wave wv owns M-tile wv (units 16wv..16wv+15).
// T_: timestep; CUR_: h read buffer (t&1); DODEC_: wave 7 computes
// y[T_-2] = dec . (previous step's bfrag, still in regs) BEFORE loading
// new frags -> dec MFMAs + global store overlap this step's read-drain.
// DOPQ_: lanes write decoder partials to pq (tail feedback).
// XSEL_: 0..3 = which lane of the quad x-register; at XSEL_==0 rotate
// xcur<-xnxt and (PFX_) prefetch the next quad's b128. XSEL_==-1: tail,
// xv = red32(pq) feedback.
// hbuf swizzle: logical 16B-chunk c of row r lives at physical chunk (c^r)&15.
// acc accumulates 2*log2e*z; h = 1 - 2/(exp2(acc)+1).
#define STEP(T_, CUR_, DODEC_, DOPQ_, XSEL_, PFX_) do {                         \
    if (isw7 && (DODEC_)) {  /* deferred dec on OLD bfrag (registers) */        \
        f32x4 dA0 = (f32x4){0.f, 0.f, 0.f, 0.f};                                \
        f32x4 dA1 = (f32x4){0.f, 0.f, 0.f, 0.f};                                \
        dA0 = MFMA16(wa_d[0], bfrag[0], dA0);                                   \
        dA1 = MFMA16(wa_d[1], bfrag[1], dA1);                                   \
        dA0 = MFMA16(wa_d[2], bfrag[2], dA0);                                   \
        dA1 = MFMA16(wa_d[3], bfrag[3], dA1);                                   \
        if (q == 0)                                                             \
            stg<F32>(out, (row0 + n) * TOUT + (T_) - 2, dA0[0] + dA1[0] + dbv); \
    }                                                                           \
    _Pragma("unroll")                                                           \
    for (int kf = 0; kf < 4; ++kf)                                              \
        bfrag[kf] = *(const f16x8*)&hbuf[CUR_][n][((((kf << 2) | q) ^ n) & 15) << 3]; \
    float xv;                                                                   \
    if ((XSEL_) < 0) {                                                          \
        xv = red32(&pq[((T_) - 1) & 1][n][0]) + dbv;                            \
    } else {                                                                    \
        if ((XSEL_) == 0) {                                                     \
            xcur = xnxt;                                                        \
            if (PFX_) xnxt = *(const f32x4*)&xs[n][(T_) + 4];                   \
        }                                                                       \
        xv = xcur[(XSEL_) & 3];                                                 \
    }                                                                           \
    f32x4 acc0, acc1;                                                           \
    _Pragma("unroll")                                                           \
    for (int r = 0; r < 4; ++r) acc0[r] = fmaf(xv, w0v[r], bsum[r]);            \
    acc1 = (f32x4){0.f, 0.f, 0.f, 0.f};                                         \
    acc0 = MFMA16(wa[0], bfrag[0], acc0);                                       \
    acc1 = MFMA16(wa[1], bfrag[1], acc1);                                       \
    acc0 = MFMA16(wa[2], bfrag[2], acc0);                                       \
    acc1 = MFMA16(wa[3], bfrag[3], acc1);                                       \
    float zs[4], ex[4], rc[4], hv[4];                                           \
    _Pragma("unroll")                                                           \
    for (int r = 0; r < 4; ++r) zs[r] = acc0[r] + acc1[r];                      \
    _Pragma("unroll")                                                           \
    for (int r = 0; r < 4; ++r) ex[r] = __builtin_amdgcn_exp2f(zs[r]);          \
    _Pragma("unroll")                                                           \
    for (int r = 0; r < 4; ++r) rc[r] = __builtin_amdgcn_rcpf(ex[r] + 1.0f);    \
    _Pragma("unroll")                                                           \
    for (int r = 0; r < 4; ++r) hv[r] = fmaf(-2.0f, rc[r], 1.0f);               \
    float p = 0.0f;                                                             \
    if (DOPQ_) {                                                                \
        _Pragma("unroll")                                                       \
        for (int r = 0; r < 4; ++r) p = fmaf(decv[r], hv[r], p);                \
    }                                                                           \
    uint2 pk;                                                                   \
    pk.x = __builtin_bit_cast(unsigned, __builtin_amdgcn_cvt_pkrtz(hv[0], hv[1])); \
    pk.y = __builtin_bit_cast(unsigned, __builtin_amdgcn_cvt_pkrtz(hv[2], hv[3])); \
    *(uint2*)&hbuf[(CUR_) ^ 1][n][((((2 * wv + (q >> 1)) ^ n) & 15) << 3) + ((q & 1) << 2)] = pk; \
    if (DOPQ_) pq[(T_) & 1][n][wv * 4 + q] = p;                                 \
    __syncthreads();                                                            \
} while (0)

template <bool F32>
__device__ void rnn_body(const void* __restrict__ xg, const void* __restrict__ h0,
                         const void* __restrict__ w0, const void* __restrict__ b0,
                         const void* __restrict__ W,  const void* __restrict__ bw,
                         const void* __restrict__ dw, const void* __restrict__ db,
                         void* __restrict__ out,
                         float (*xs)[XSTR], _Float16 (*hbuf)[BM][HH],
                         float (*pq)[BM][PQS])
{
    const int tid  = threadIdx.x;
    const int lane = tid & 63;
    const int wv   = tid >> 6;        // 0..7 (= m-tile index)
    const int q    = lane >> 4;       // 0..3
    const int n    = lane & 15;       // batch col / A-row-in-tile
    const int row0 = blockIdx.x * BM;
    const bool isw7 = (wv == 7);      // wave-uniform: decoder wave

    // stage x (fp32 in LDS)
    for (int idx = tid; idx < BM * TT; idx += 512) {
        const int rr = idx >> 9, t2 = idx & (TT - 1);
        xs[rr][t2] = ldg<F32>(xg, (row0 + rr) * TT + t2);
    }
    // stage h0 as fp16 (swizzled: chunk c of row rr -> (c^rr)&15)
    for (int idx = tid; idx < BM * HH; idx += 512) {
        const int rr = idx >> 7, ii = idx & (HH - 1);
        const int po = ((((ii >> 3) ^ rr) & 15) << 3) + (ii & 7);
        hbuf[0][rr][po] = (_Float16)ldg<F32>(h0, (row0 + rr) * HH + ii);
    }

    // preload W fragments (A-operand: A[m=lane&15][k=q*8+j]) as fp16,
    // PRE-SCALED by 2*log2e so the accumulator is the exp2 argument.
    f16x8 wa[4];
    {
        const int ia = wv * 16 + n;   // W row (output unit)
        #pragma unroll
        for (int kf = 0; kf < 4; ++kf) {
            const int kb = kf * 32 + q * 8;
            f16x8 fr;
            #pragma unroll
            for (int j = 0; j < 8; ++j)
                fr[j] = (_Float16)(TWOLOG2E * ldg<F32>(W, ia * HH + kb + j));
            wa[kf] = fr;
        }
    }
    // dec tile (wave 7): A row 0 = dec_w (UNscaled - operates on h), rows 1..15 = 0
    f16x8 wa_d[4] = {};
    if (isw7) {
        #pragma unroll
        for (int kf = 0; kf < 4; ++kf) {
            const int kb = kf * 32 + q * 8;
            f16x8 fr = {};
            if (n == 0) {
                #pragma unroll
                for (int j = 0; j < 8; ++j) fr[j] = (_Float16)ldg<F32>(dw, kb + j);
            }
            wa_d[kf] = fr;
        }
    }
    // epilogue constants (C-layout rows: i = wv*16 + q*4 + r), pre-scaled
    float bsum[4], w0v[4], decv[4];
    #pragma unroll
    for (int r = 0; r < 4; ++r) {
        const int ic = wv * 16 + q * 4 + r;
        bsum[r] = TWOLOG2E * (ldg<F32>(b0, ic) + ldg<F32>(bw, ic));
        w0v[r]  = TWOLOG2E * ldg<F32>(w0, ic);
        decv[r] = ldg<F32>(dw, ic);
    }
    const float dbv = ldg<F32>(db, 0);

    __syncthreads();

    f16x8 bfrag[4];                     // persists across steps (dec uses prev)
    f32x4 xcur, xnxt;
    xnxt = *(const f32x4*)&xs[n][0];    // quad 0's x

    // quad 0: t = 0..3 (dec starts at t=2 -> y[0])
    STEP(0, 0, false, false, 0, true);
    STEP(1, 1, false, false, 1, false);
    STEP(2, 0, true,  false, 2, false);
    STEP(3, 1, true,  false, 3, false);

    // main quads: t = 4..507 (prefetch next quad's x at each quad head)
    #pragma unroll 1
    for (int t = 4; t < 508; t += 4) {
        STEP(t,     0, true, false, 0, true);
        STEP(t + 1, 1, true, false, 1, false);
        STEP(t + 2, 0, true, false, 2, false);
        STEP(t + 3, 1, true, false, 3, false);
    }

    // quad 127: t = 508..511 (last x quad; step 511 starts pq feedback)
    STEP(508, 0, true, false, 0, false);
    STEP(509, 1, true, false, 1, false);
    STEP(510, 0, true, false, 2, false);
    STEP(511, 1, true, true,  3, false);

    // quad 128: tail t = 512..515, xv = y[t-1] via pq reduce
    STEP(512, 0, true, true, -1, false);
    STEP(513, 1, true, true, -1, false);
    STEP(514, 0, true, true, -1, false);
    STEP(515, 1, true, true, -1, false);

    // post: y[514] from final bfrag (= ys[514]); y[515] via pq[1] reduce
    if (isw7) {
        f32x4 dA0 = (f32x4){0.f, 0.f, 0.f, 0.f};
        f32x4 dA1 = (f32x4){0.f, 0.f, 0.f, 0.f};
        dA0 = MFMA16(wa_d[0], bfrag[0], dA0);
        dA1 = MFMA16(wa_d[1], bfrag[1], dA1);
        dA0 = MFMA16(wa_d[2], bfrag[2], dA0);
        dA1 = MFMA16(wa_d[3], bfrag[3], dA1);
        if (q == 0) {
            stg<F32>(out, (row0 + n) * TOUT + 514, dA0[0] + dA1[0] + dbv);
            stg<F32>(out, (row0 + n) * TOUT + 515, red32(&pq[1][n][0]) + dbv);
        }
    }
}

__global__ __launch_bounds__(512, 1)
void rnn_mfma(const void* __restrict__ xg, const void* __restrict__ h0,
              const void* __restrict__ w0, const void* __restrict__ b0,
              const void* __restrict__ W,  const void* __restrict__ bw,
              const void* __restrict__ dw, const void* __restrict__ db,
              void* __restrict__ out, const int* __restrict__ flag)
{
    __shared__ float xs[BM][XSTR];                          // 33 KB
    __shared__ __align__(16) _Float16 hbuf[2][BM][HH];      // 8 KB
    __shared__ __align__(16) float pq[2][BM][PQS];          // 4.6 KB

    const int f = *(volatile const int*)flag;  // block-uniform
    if (f) rnn_body<true >(xg, h0, w0, b0, W, bw, dw, db, out, xs, hbuf, pq);
    else   rnn_body<false>(xg, h0, w0, b0, W, bw, dw, db, out, xs, hbuf, pq);
}

extern "C" void kernel_launch(void* const* d_in, const int* in_sizes, int n_in,
                              void* d_out, int out_size, void* d_ws, size_t ws_size,
                              hipStream_t stream) {
    int* flag = (int*)d_ws;
    detect_dtype<<<1, 64, 0, stream>>>(d_in[4], flag);  // probe fc_w
    rnn_mfma<<<BB / BM, 512, 0, stream>>>(d_in[0], d_in[1], d_in[2], d_in[3],
                                          d_in[4], d_in[5], d_in[6], d_in[7],
                                          d_out, flag);
}